// Round 1
// baseline (758.313 us; speedup 1.0000x reference)
//
#include <hip/hip_runtime.h>

#define NN 50000
#define NE 640000
#define DF 128

// ---------------- CSR build ----------------

__global__ __launch_bounds__(256) void k_init_deg(float* __restrict__ deg) {
  int i = blockIdx.x * 256 + threadIdx.x;
  if (i < NN) deg[i] = 1.0f;  // self-loop
}

__global__ __launch_bounds__(256) void k_count(const int* __restrict__ ei, float* __restrict__ deg) {
  int e = blockIdx.x * 256 + threadIdx.x;
  if (e < NE) atomicAdd(&deg[ei[NE + e]], 1.0f);
}

// single block: exclusive prefix sum of real-edge counts ((int)deg - 1)
__global__ __launch_bounds__(1024) void k_scan(const float* __restrict__ deg,
                                               int* __restrict__ off, int* __restrict__ fill) {
  __shared__ int sums[1024];
  int tid = threadIdx.x;
  const int chunk = (NN + 1023) / 1024;  // 49
  int b = tid * chunk;
  int e = min(b + chunk, NN);
  int s = 0;
  for (int i = b; i < e; ++i) s += (int)deg[i] - 1;
  sums[tid] = s;
  __syncthreads();
  for (int d = 1; d < 1024; d <<= 1) {
    int v = (tid >= d) ? sums[tid - d] : 0;
    __syncthreads();
    sums[tid] += v;
    __syncthreads();
  }
  int run = (tid > 0) ? sums[tid - 1] : 0;
  for (int i = b; i < e; ++i) {
    off[i] = run;
    fill[i] = run;
    run += (int)deg[i] - 1;
  }
  if (tid == 1023) off[NN] = run;
}

__global__ __launch_bounds__(256) void k_rsqrt(float* __restrict__ deg) {
  int i = blockIdx.x * 256 + threadIdx.x;
  if (i < NN) deg[i] = rsqrtf(deg[i]);  // deg >= 1 always (self-loop)
}

__global__ __launch_bounds__(256) void k_scatter(const int* __restrict__ ei, const float* __restrict__ dinv,
                                                 int* __restrict__ fill, int* __restrict__ ssrc,
                                                 float* __restrict__ sw) {
  int e = blockIdx.x * 256 + threadIdx.x;
  if (e >= NE) return;
  int s = ei[e];
  int d = ei[NE + e];
  int pos = atomicAdd(&fill[d], 1);
  ssrc[pos] = s;
  sw[pos] = dinv[s] * dinv[d];
}

// ---------------- GEMM: C[M,128] = A[M,128] @ W[128,128] ----------------
// block = 256 threads, 32 rows x 128 cols per block; A tile in LDS (132-pad),
// W streamed from global (L1/L2-hot, 8-way broadcast within wave).

__global__ __launch_bounds__(256) void k_gemm(const float* __restrict__ A,
                                              const float* __restrict__ W,
                                              float* __restrict__ C) {
  __shared__ float As[32][132];  // 528 B row stride: 16B-aligned, conflict-free for our read pattern
  int tid = threadIdx.x;
  int brow = blockIdx.x * 32;
  for (int idx = tid; idx < 32 * 32; idx += 256) {
    int r = idx >> 5, c4 = idx & 31;
    int row = brow + r;
    float4 v = make_float4(0.f, 0.f, 0.f, 0.f);
    if (row < NN) v = ((const float4*)(A + (size_t)row * DF))[c4];
    *(float4*)&As[r][c4 * 4] = v;
  }
  __syncthreads();

  int r = tid >> 3;            // 0..31  (8 lanes share a row -> LDS broadcast)
  int col0 = (tid & 7) * 16;   // 8 col-groups x 16 cols
  float4 a0 = make_float4(0.f, 0.f, 0.f, 0.f);
  float4 a1 = a0, a2 = a0, a3 = a0;

#pragma unroll 4
  for (int k = 0; k < DF; ++k) {
    float a = As[r][k];
    const float4* wr = (const float4*)(W + k * DF + col0);
    float4 w0 = wr[0], w1 = wr[1], w2 = wr[2], w3 = wr[3];
    a0.x = fmaf(a, w0.x, a0.x); a0.y = fmaf(a, w0.y, a0.y);
    a0.z = fmaf(a, w0.z, a0.z); a0.w = fmaf(a, w0.w, a0.w);
    a1.x = fmaf(a, w1.x, a1.x); a1.y = fmaf(a, w1.y, a1.y);
    a1.z = fmaf(a, w1.z, a1.z); a1.w = fmaf(a, w1.w, a1.w);
    a2.x = fmaf(a, w2.x, a2.x); a2.y = fmaf(a, w2.y, a2.y);
    a2.z = fmaf(a, w2.z, a2.z); a2.w = fmaf(a, w2.w, a2.w);
    a3.x = fmaf(a, w3.x, a3.x); a3.y = fmaf(a, w3.y, a3.y);
    a3.z = fmaf(a, w3.z, a3.z); a3.w = fmaf(a, w3.w, a3.w);
  }

  int row = brow + r;
  if (row < NN) {
    float4* cr = (float4*)(C + (size_t)row * DF + col0);
    cr[0] = a0; cr[1] = a1; cr[2] = a2; cr[3] = a3;
  }
}

// ---------------- Aggregation: one wave per node, float2 per lane ----------------
// out[i] = relu?( sum_{e: dst=i} h[src_e]*w_e + h[i]*dinv[i]^2 + bias )

__global__ __launch_bounds__(256) void k_agg(const float* __restrict__ h, const float* __restrict__ dinv,
                                             const int* __restrict__ off, const int* __restrict__ ssrc,
                                             const float* __restrict__ sw, const float* __restrict__ bias,
                                             float* __restrict__ out, int do_relu) {
  int gw = (blockIdx.x * 256 + threadIdx.x) >> 6;  // global wave id = node id
  int lane = threadIdx.x & 63;
  if (gw >= NN) return;

  float di = dinv[gw];
  float w0 = di * di;
  float2 acc = ((const float2*)(h + (size_t)gw * DF))[lane];
  acc.x *= w0;
  acc.y *= w0;

  int e = off[gw], e1 = off[gw + 1];
  for (; e < e1; ++e) {
    int s = ssrc[e];
    float w = sw[e];
    float2 v = ((const float2*)(h + (size_t)s * DF))[lane];
    acc.x = fmaf(v.x, w, acc.x);
    acc.y = fmaf(v.y, w, acc.y);
  }

  float2 b = ((const float2*)bias)[lane];
  acc.x += b.x;
  acc.y += b.y;
  if (do_relu) {
    acc.x = fmaxf(acc.x, 0.f);
    acc.y = fmaxf(acc.y, 0.f);
  }
  ((float2*)(out + (size_t)gw * DF))[lane] = acc;
}

// ---------------- launcher ----------------

extern "C" void kernel_launch(void* const* d_in, const int* in_sizes, int n_in,
                              void* d_out, int out_size, void* d_ws, size_t ws_size,
                              hipStream_t stream) {
  const float* x  = (const float*)d_in[0];
  const int*   ei = (const int*)d_in[1];   // [2, NE] int32
  const float* W1 = (const float*)d_in[2];
  const float* b1 = (const float*)d_in[3];
  const float* W2 = (const float*)d_in[4];
  const float* b2 = (const float*)d_in[5];
  float* out = (float*)d_out;

  char* ws = (char*)d_ws;
  float* hA   = (float*)ws; ws += (size_t)NN * DF * 4;  // 25.6 MB
  int*   ssrc = (int*)ws;   ws += (size_t)NE * 4;       // 2.56 MB
  float* sw   = (float*)ws; ws += (size_t)NE * 4;       // 2.56 MB
  float* deg  = (float*)ws; ws += (size_t)NN * 4;       // becomes dinv after k_rsqrt
  int*   fill = (int*)ws;   ws += (size_t)NN * 4;
  int*   off  = (int*)ws;   ws += (size_t)(NN + 1) * 4;
  float* hB = out;  // reuse d_out as layer-1 activation scratch (fully rewritten by final agg)

  k_init_deg<<<(NN + 255) / 256, 256, 0, stream>>>(deg);
  k_count<<<(NE + 255) / 256, 256, 0, stream>>>(ei, deg);
  k_scan<<<1, 1024, 0, stream>>>(deg, off, fill);
  k_rsqrt<<<(NN + 255) / 256, 256, 0, stream>>>(deg);
  k_scatter<<<(NE + 255) / 256, 256, 0, stream>>>(ei, deg, fill, ssrc, sw);

  k_gemm<<<(NN + 31) / 32, 256, 0, stream>>>(x, W1, hA);
  k_agg<<<(NN * 64 + 255) / 256, 256, 0, stream>>>(hA, deg, off, ssrc, sw, b1, hB, 1);
  k_gemm<<<(NN + 31) / 32, 256, 0, stream>>>(hB, W2, hA);
  k_agg<<<(NN * 64 + 255) / 256, 256, 0, stream>>>(hA, deg, off, ssrc, sw, b2, out, 0);
}

// Round 2
// 358.599 us; speedup vs baseline: 2.1147x; 2.1147x over previous
//
#include <hip/hip_runtime.h>

#define NN 50000
#define NE 640000
#define DF 128
#define BM 64
#define BK 32

// ---------------- CSR build ----------------

__global__ __launch_bounds__(256) void k_init_deg(float* __restrict__ deg) {
  int i = blockIdx.x * 256 + threadIdx.x;
  if (i < NN) deg[i] = 1.0f;  // self-loop
}

__global__ __launch_bounds__(256) void k_count(const int* __restrict__ ei, float* __restrict__ deg) {
  int e = blockIdx.x * 256 + threadIdx.x;
  if (e < NE) atomicAdd(&deg[ei[NE + e]], 1.0f);
}

// single block: exclusive prefix sum of real-edge counts ((int)deg - 1)
__global__ __launch_bounds__(1024) void k_scan(const float* __restrict__ deg,
                                               int* __restrict__ off, int* __restrict__ fill) {
  __shared__ int sums[1024];
  int tid = threadIdx.x;
  const int chunk = (NN + 1023) / 1024;  // 49
  int b = tid * chunk;
  int e = min(b + chunk, NN);
  int s = 0;
  for (int i = b; i < e; ++i) s += (int)deg[i] - 1;
  sums[tid] = s;
  __syncthreads();
  for (int d = 1; d < 1024; d <<= 1) {
    int v = (tid >= d) ? sums[tid - d] : 0;
    __syncthreads();
    sums[tid] += v;
    __syncthreads();
  }
  int run = (tid > 0) ? sums[tid - 1] : 0;
  for (int i = b; i < e; ++i) {
    off[i] = run;
    fill[i] = run;
    run += (int)deg[i] - 1;
  }
  if (tid == 1023) off[NN] = run;
}

__global__ __launch_bounds__(256) void k_rsqrt(float* __restrict__ deg) {
  int i = blockIdx.x * 256 + threadIdx.x;
  if (i < NN) deg[i] = rsqrtf(deg[i]);
}

__global__ __launch_bounds__(256) void k_scatter(const int* __restrict__ ei, const float* __restrict__ dinv,
                                                 int* __restrict__ fill, int* __restrict__ ssrc,
                                                 float* __restrict__ sw) {
  int e = blockIdx.x * 256 + threadIdx.x;
  if (e >= NE) return;
  int s = ei[e];
  int d = ei[NE + e];
  int pos = atomicAdd(&fill[d], 1);
  ssrc[pos] = s;
  sw[pos] = dinv[s] * dinv[d];
}

// ---------------- GEMM: C[M,128] = A[M,128] @ W[128,128] ----------------
// 64x128 tile per 256-thread block, K-tiled by 32. A transposed into LDS
// (As[kk][m], stride 68 words -> 16B-aligned rows, broadcast reads).
// W tile staged in LDS (contiguous rows -> conflict-free b128 reads).
// Thread tile: 8 rows x 4 cols = 32 acc -> 3 ds_read_b128 per 32 FMA.

__global__ __launch_bounds__(256) void k_gemm(const float* __restrict__ A,
                                              const float* __restrict__ W,
                                              float* __restrict__ C) {
  __shared__ float As[BK][BM + 4];  // 68-float stride
  __shared__ float Ws[BK][DF];

  int tid = threadIdx.x;
  int brow = blockIdx.x * BM;

  int rg = tid >> 5;       // 0..7 -> rows rg*8 .. rg*8+7
  int cg = tid & 31;       // cols cg*4 .. cg*4+3

  int ar = tid >> 2;        // 0..63: A-stage row
  int ac = (tid & 3) * 8;   // A-stage col chunk (8 floats)

  float4 acc[8];
#pragma unroll
  for (int r = 0; r < 8; ++r) acc[r] = make_float4(0.f, 0.f, 0.f, 0.f);

  for (int k0 = 0; k0 < DF; k0 += BK) {
    // global loads into regs (overlap previous tile's compute)
    float4 a0 = make_float4(0.f, 0.f, 0.f, 0.f), a1 = a0;
    if (brow + ar < NN) {
      const float4* ap = (const float4*)(A + (size_t)(brow + ar) * DF + k0 + ac);
      a0 = ap[0];
      a1 = ap[1];
    }
    const float4* wg = (const float4*)(W + (size_t)k0 * DF);
    float4 w0 = wg[tid], w1 = wg[tid + 256], w2 = wg[tid + 512], w3 = wg[tid + 768];

    __syncthreads();  // previous tile compute done before overwrite

    As[ac + 0][ar] = a0.x; As[ac + 1][ar] = a0.y;
    As[ac + 2][ar] = a0.z; As[ac + 3][ar] = a0.w;
    As[ac + 4][ar] = a1.x; As[ac + 5][ar] = a1.y;
    As[ac + 6][ar] = a1.z; As[ac + 7][ar] = a1.w;

    float4* wl = (float4*)&Ws[0][0];
    wl[tid] = w0; wl[tid + 256] = w1; wl[tid + 512] = w2; wl[tid + 768] = w3;

    __syncthreads();

#pragma unroll 4
    for (int kk = 0; kk < BK; ++kk) {
      float4 av0 = *(const float4*)&As[kk][rg * 8];
      float4 av1 = *(const float4*)&As[kk][rg * 8 + 4];
      float4 wv = *(const float4*)&Ws[kk][cg * 4];
      float a_[8] = {av0.x, av0.y, av0.z, av0.w, av1.x, av1.y, av1.z, av1.w};
#pragma unroll
      for (int r = 0; r < 8; ++r) {
        acc[r].x = fmaf(a_[r], wv.x, acc[r].x);
        acc[r].y = fmaf(a_[r], wv.y, acc[r].y);
        acc[r].z = fmaf(a_[r], wv.z, acc[r].z);
        acc[r].w = fmaf(a_[r], wv.w, acc[r].w);
      }
    }
  }

#pragma unroll
  for (int r = 0; r < 8; ++r) {
    int row = brow + rg * 8 + r;
    if (row < NN) *(float4*)(C + (size_t)row * DF + cg * 4) = acc[r];
  }
}

// ---------------- Aggregation: one wave per node, unroll x4 ----------------

__global__ __launch_bounds__(256) void k_agg(const float* __restrict__ h, const float* __restrict__ dinv,
                                             const int* __restrict__ off, const int* __restrict__ ssrc,
                                             const float* __restrict__ sw, const float* __restrict__ bias,
                                             float* __restrict__ out, int do_relu) {
  int gw = (blockIdx.x * 256 + threadIdx.x) >> 6;
  int lane = threadIdx.x & 63;
  if (gw >= NN) return;

  float di = dinv[gw];
  float w0 = di * di;
  float2 acc0 = ((const float2*)(h + (size_t)gw * DF))[lane];
  acc0.x *= w0;
  acc0.y *= w0;
  float2 acc1 = make_float2(0.f, 0.f), acc2 = acc1, acc3 = acc1;

  int e = off[gw], e1 = off[gw + 1];
  for (; e + 4 <= e1; e += 4) {
    int s0 = ssrc[e], s1 = ssrc[e + 1], s2 = ssrc[e + 2], s3 = ssrc[e + 3];
    float we0 = sw[e], we1 = sw[e + 1], we2 = sw[e + 2], we3 = sw[e + 3];
    float2 v0 = ((const float2*)(h + (size_t)s0 * DF))[lane];
    float2 v1 = ((const float2*)(h + (size_t)s1 * DF))[lane];
    float2 v2 = ((const float2*)(h + (size_t)s2 * DF))[lane];
    float2 v3 = ((const float2*)(h + (size_t)s3 * DF))[lane];
    acc0.x = fmaf(v0.x, we0, acc0.x); acc0.y = fmaf(v0.y, we0, acc0.y);
    acc1.x = fmaf(v1.x, we1, acc1.x); acc1.y = fmaf(v1.y, we1, acc1.y);
    acc2.x = fmaf(v2.x, we2, acc2.x); acc2.y = fmaf(v2.y, we2, acc2.y);
    acc3.x = fmaf(v3.x, we3, acc3.x); acc3.y = fmaf(v3.y, we3, acc3.y);
  }
  for (; e < e1; ++e) {
    int s = ssrc[e];
    float w = sw[e];
    float2 v = ((const float2*)(h + (size_t)s * DF))[lane];
    acc0.x = fmaf(v.x, w, acc0.x);
    acc0.y = fmaf(v.y, w, acc0.y);
  }

  acc0.x += acc1.x + acc2.x + acc3.x;
  acc0.y += acc1.y + acc2.y + acc3.y;

  float2 b = ((const float2*)bias)[lane];
  acc0.x += b.x;
  acc0.y += b.y;
  if (do_relu) {
    acc0.x = fmaxf(acc0.x, 0.f);
    acc0.y = fmaxf(acc0.y, 0.f);
  }
  ((float2*)(out + (size_t)gw * DF))[lane] = acc0;
}

// ---------------- launcher ----------------

extern "C" void kernel_launch(void* const* d_in, const int* in_sizes, int n_in,
                              void* d_out, int out_size, void* d_ws, size_t ws_size,
                              hipStream_t stream) {
  const float* x  = (const float*)d_in[0];
  const int*   ei = (const int*)d_in[1];
  const float* W1 = (const float*)d_in[2];
  const float* b1 = (const float*)d_in[3];
  const float* W2 = (const float*)d_in[4];
  const float* b2 = (const float*)d_in[5];
  float* out = (float*)d_out;

  char* ws = (char*)d_ws;
  float* hA   = (float*)ws; ws += (size_t)NN * DF * 4;
  int*   ssrc = (int*)ws;   ws += (size_t)NE * 4;
  float* sw   = (float*)ws; ws += (size_t)NE * 4;
  float* deg  = (float*)ws; ws += (size_t)NN * 4;  // becomes dinv
  int*   fill = (int*)ws;   ws += (size_t)NN * 4;
  int*   off  = (int*)ws;   ws += (size_t)(NN + 1) * 4;
  float* hB = out;  // layer-1 activation scratch (fully rewritten by final agg)

  k_init_deg<<<(NN + 255) / 256, 256, 0, stream>>>(deg);
  k_count<<<(NE + 255) / 256, 256, 0, stream>>>(ei, deg);
  k_scan<<<1, 1024, 0, stream>>>(deg, off, fill);
  k_rsqrt<<<(NN + 255) / 256, 256, 0, stream>>>(deg);
  k_scatter<<<(NE + 255) / 256, 256, 0, stream>>>(ei, deg, fill, ssrc, sw);

  k_gemm<<<(NN + BM - 1) / BM, 256, 0, stream>>>(x, W1, hA);
  k_agg<<<(NN * 64 + 255) / 256, 256, 0, stream>>>(hA, deg, off, ssrc, sw, b1, hB, 1);
  k_gemm<<<(NN + BM - 1) / BM, 256, 0, stream>>>(hB, W2, hA);
  k_agg<<<(NN * 64 + 255) / 256, 256, 0, stream>>>(hA, deg, off, ssrc, sw, b2, out, 0);
}

// Round 3
// 237.918 us; speedup vs baseline: 3.1873x; 1.5072x over previous
//
#include <hip/hip_runtime.h>

#define NN 50000
#define NE 640000
#define DF 128
#define BM 64
#define BK 32
#define NB ((NN + 255) / 256)  // 196 scan blocks

// ---------------- CSR build ----------------

__global__ __launch_bounds__(256) void k_count(const int* __restrict__ ei, int* __restrict__ degi) {
  int e = blockIdx.x * 256 + threadIdx.x;
  if (e < NE) atomicAdd(&degi[ei[NE + e]], 1);
}

__global__ __launch_bounds__(256) void k_blocksum(const int* __restrict__ degi, int* __restrict__ bsum) {
  int i = blockIdx.x * 256 + threadIdx.x;
  int v = (i < NN) ? degi[i] : 0;
#pragma unroll
  for (int d = 32; d > 0; d >>= 1) v += __shfl_down(v, d, 64);
  __shared__ int s[4];
  if ((threadIdx.x & 63) == 0) s[threadIdx.x >> 6] = v;
  __syncthreads();
  if (threadIdx.x == 0) bsum[blockIdx.x] = s[0] + s[1] + s[2] + s[3];
}

__global__ __launch_bounds__(256) void k_scan_small(const int* __restrict__ bsum, int* __restrict__ bpre) {
  __shared__ int s[256];
  int tid = threadIdx.x;
  int v = (tid < NB) ? bsum[tid] : 0;
  s[tid] = v;
  __syncthreads();
  for (int d = 1; d < 256; d <<= 1) {
    int t = (tid >= d) ? s[tid - d] : 0;
    __syncthreads();
    s[tid] += t;
    __syncthreads();
  }
  if (tid < NB) bpre[tid] = s[tid] - v;  // exclusive
}

// in-block exclusive scan + block prefix; fuses dinv = rsqrtf(deg+1)
__global__ __launch_bounds__(256) void k_offsets(const int* __restrict__ degi, const int* __restrict__ bpre,
                                                 int* __restrict__ off, int* __restrict__ fill,
                                                 float* __restrict__ dinv) {
  __shared__ int s[256];
  int tid = threadIdx.x;
  int i = blockIdx.x * 256 + tid;
  int v = (i < NN) ? degi[i] : 0;
  s[tid] = v;
  __syncthreads();
  for (int d = 1; d < 256; d <<= 1) {
    int t = (tid >= d) ? s[tid - d] : 0;
    __syncthreads();
    s[tid] += t;
    __syncthreads();
  }
  if (i < NN) {
    int o = bpre[blockIdx.x] + s[tid] - v;
    off[i] = o;
    fill[i] = o;
    dinv[i] = rsqrtf((float)(v + 1));  // +1 self-loop
  }
  if (i == NN - 1) off[NN] = NE;  // total real edges is constant
}

__global__ __launch_bounds__(256) void k_scatter(const int* __restrict__ ei, const float* __restrict__ dinv,
                                                 int* __restrict__ fill, int* __restrict__ ssrc,
                                                 float* __restrict__ sw) {
  int e = blockIdx.x * 256 + threadIdx.x;
  if (e >= NE) return;
  int s = ei[e];
  int d = ei[NE + e];
  int pos = atomicAdd(&fill[d], 1);
  ssrc[pos] = s;
  sw[pos] = dinv[s] * dinv[d];
}

// ---------------- GEMM: C[M,128] = A[M,128] @ W[128,128] ----------------

__global__ __launch_bounds__(256) void k_gemm(const float* __restrict__ A,
                                              const float* __restrict__ W,
                                              float* __restrict__ C) {
  __shared__ float As[BK][BM + 4];
  __shared__ float Ws[BK][DF];

  int tid = threadIdx.x;
  int brow = blockIdx.x * BM;

  int rg = tid >> 5;
  int cg = tid & 31;
  int ar = tid >> 2;
  int ac = (tid & 3) * 8;

  float4 acc[8];
#pragma unroll
  for (int r = 0; r < 8; ++r) acc[r] = make_float4(0.f, 0.f, 0.f, 0.f);

  for (int k0 = 0; k0 < DF; k0 += BK) {
    float4 a0 = make_float4(0.f, 0.f, 0.f, 0.f), a1 = a0;
    if (brow + ar < NN) {
      const float4* ap = (const float4*)(A + (size_t)(brow + ar) * DF + k0 + ac);
      a0 = ap[0];
      a1 = ap[1];
    }
    const float4* wg = (const float4*)(W + (size_t)k0 * DF);
    float4 w0 = wg[tid], w1 = wg[tid + 256], w2 = wg[tid + 512], w3 = wg[tid + 768];

    __syncthreads();

    As[ac + 0][ar] = a0.x; As[ac + 1][ar] = a0.y;
    As[ac + 2][ar] = a0.z; As[ac + 3][ar] = a0.w;
    As[ac + 4][ar] = a1.x; As[ac + 5][ar] = a1.y;
    As[ac + 6][ar] = a1.z; As[ac + 7][ar] = a1.w;

    float4* wl = (float4*)&Ws[0][0];
    wl[tid] = w0; wl[tid + 256] = w1; wl[tid + 512] = w2; wl[tid + 768] = w3;

    __syncthreads();

#pragma unroll 4
    for (int kk = 0; kk < BK; ++kk) {
      float4 av0 = *(const float4*)&As[kk][rg * 8];
      float4 av1 = *(const float4*)&As[kk][rg * 8 + 4];
      float4 wv = *(const float4*)&Ws[kk][cg * 4];
      float a_[8] = {av0.x, av0.y, av0.z, av0.w, av1.x, av1.y, av1.z, av1.w};
#pragma unroll
      for (int r = 0; r < 8; ++r) {
        acc[r].x = fmaf(a_[r], wv.x, acc[r].x);
        acc[r].y = fmaf(a_[r], wv.y, acc[r].y);
        acc[r].z = fmaf(a_[r], wv.z, acc[r].z);
        acc[r].w = fmaf(a_[r], wv.w, acc[r].w);
      }
    }
  }

#pragma unroll
  for (int r = 0; r < 8; ++r) {
    int row = brow + rg * 8 + r;
    if (row < NN) *(float4*)(C + (size_t)row * DF + cg * 4) = acc[r];
  }
}

// ---------------- Aggregation: one wave per node, 8 gathers in flight ----------------

__global__ __launch_bounds__(256) void k_agg(const float* __restrict__ h, const float* __restrict__ dinv,
                                             const int* __restrict__ off, const int* __restrict__ ssrc,
                                             const float* __restrict__ sw, const float* __restrict__ bias,
                                             float* __restrict__ out, int do_relu) {
  int gw = (blockIdx.x * 256 + threadIdx.x) >> 6;
  int lane = threadIdx.x & 63;
  if (gw >= NN) return;

  float di = dinv[gw];
  float w0s = di * di;
  float2 hs = ((const float2*)(h + (size_t)gw * DF))[lane];
  float2 a0 = make_float2(hs.x * w0s, hs.y * w0s);
  float2 a1 = make_float2(0.f, 0.f), a2 = a1, a3 = a1;

  int e = off[gw], e1 = off[gw + 1];
  for (; e < e1; e += 8) {
    int last = e1 - 1;
    int i1 = min(e + 1, last), i2 = min(e + 2, last), i3 = min(e + 3, last);
    int i4 = min(e + 4, last), i5 = min(e + 5, last), i6 = min(e + 6, last), i7 = min(e + 7, last);
    int s0 = ssrc[e],  s1 = ssrc[i1], s2 = ssrc[i2], s3 = ssrc[i3];
    int s4 = ssrc[i4], s5 = ssrc[i5], s6 = ssrc[i6], s7 = ssrc[i7];
    float w0 = sw[e];
    float w1 = (e + 1 <= last) ? sw[i1] : 0.f;
    float w2 = (e + 2 <= last) ? sw[i2] : 0.f;
    float w3 = (e + 3 <= last) ? sw[i3] : 0.f;
    float w4 = (e + 4 <= last) ? sw[i4] : 0.f;
    float w5 = (e + 5 <= last) ? sw[i5] : 0.f;
    float w6 = (e + 6 <= last) ? sw[i6] : 0.f;
    float w7 = (e + 7 <= last) ? sw[i7] : 0.f;
    float2 v0 = ((const float2*)(h + (size_t)s0 * DF))[lane];
    float2 v1 = ((const float2*)(h + (size_t)s1 * DF))[lane];
    float2 v2 = ((const float2*)(h + (size_t)s2 * DF))[lane];
    float2 v3 = ((const float2*)(h + (size_t)s3 * DF))[lane];
    float2 v4 = ((const float2*)(h + (size_t)s4 * DF))[lane];
    float2 v5 = ((const float2*)(h + (size_t)s5 * DF))[lane];
    float2 v6 = ((const float2*)(h + (size_t)s6 * DF))[lane];
    float2 v7 = ((const float2*)(h + (size_t)s7 * DF))[lane];
    a0.x = fmaf(v0.x, w0, a0.x); a0.y = fmaf(v0.y, w0, a0.y);
    a1.x = fmaf(v1.x, w1, a1.x); a1.y = fmaf(v1.y, w1, a1.y);
    a2.x = fmaf(v2.x, w2, a2.x); a2.y = fmaf(v2.y, w2, a2.y);
    a3.x = fmaf(v3.x, w3, a3.x); a3.y = fmaf(v3.y, w3, a3.y);
    a0.x = fmaf(v4.x, w4, a0.x); a0.y = fmaf(v4.y, w4, a0.y);
    a1.x = fmaf(v5.x, w5, a1.x); a1.y = fmaf(v5.y, w5, a1.y);
    a2.x = fmaf(v6.x, w6, a2.x); a2.y = fmaf(v6.y, w6, a2.y);
    a3.x = fmaf(v7.x, w7, a3.x); a3.y = fmaf(v7.y, w7, a3.y);
  }

  a0.x += a1.x + a2.x + a3.x;
  a0.y += a1.y + a2.y + a3.y;

  float2 b = ((const float2*)bias)[lane];
  a0.x += b.x;
  a0.y += b.y;
  if (do_relu) {
    a0.x = fmaxf(a0.x, 0.f);
    a0.y = fmaxf(a0.y, 0.f);
  }
  ((float2*)(out + (size_t)gw * DF))[lane] = a0;
}

// ---------------- launcher ----------------

extern "C" void kernel_launch(void* const* d_in, const int* in_sizes, int n_in,
                              void* d_out, int out_size, void* d_ws, size_t ws_size,
                              hipStream_t stream) {
  const float* x  = (const float*)d_in[0];
  const int*   ei = (const int*)d_in[1];
  const float* W1 = (const float*)d_in[2];
  const float* b1 = (const float*)d_in[3];
  const float* W2 = (const float*)d_in[4];
  const float* b2 = (const float*)d_in[5];
  float* out = (float*)d_out;

  char* ws = (char*)d_ws;
  float* hA   = (float*)ws; ws += (size_t)NN * DF * 4;
  int*   ssrc = (int*)ws;   ws += (size_t)NE * 4;
  float* sw   = (float*)ws; ws += (size_t)NE * 4;
  int*   degi = (int*)ws;   ws += (size_t)NN * 4;
  float* dinv = (float*)ws; ws += (size_t)NN * 4;
  int*   fill = (int*)ws;   ws += (size_t)NN * 4;
  int*   off  = (int*)ws;   ws += (size_t)(NN + 1) * 4;
  int*   bsum = (int*)ws;   ws += (size_t)NB * 4;
  int*   bpre = (int*)ws;   ws += (size_t)NB * 4;
  float* hB = out;  // layer-1 activation scratch (fully rewritten by final agg)

  hipMemsetAsync(degi, 0, (size_t)NN * 4, stream);
  k_count<<<(NE + 255) / 256, 256, 0, stream>>>(ei, degi);
  k_blocksum<<<NB, 256, 0, stream>>>(degi, bsum);
  k_scan_small<<<1, 256, 0, stream>>>(bsum, bpre);
  k_offsets<<<NB, 256, 0, stream>>>(degi, bpre, off, fill, dinv);
  k_scatter<<<(NE + 255) / 256, 256, 0, stream>>>(ei, dinv, fill, ssrc, sw);

  k_gemm<<<(NN + BM - 1) / BM, 256, 0, stream>>>(x, W1, hA);
  k_agg<<<(NN * 64 + 255) / 256, 256, 0, stream>>>(hA, dinv, off, ssrc, sw, b1, hB, 1);
  k_gemm<<<(NN + BM - 1) / BM, 256, 0, stream>>>(hB, W2, hA);
  k_agg<<<(NN * 64 + 255) / 256, 256, 0, stream>>>(hA, dinv, off, ssrc, sw, b2, out, 0);
}

// Round 4
// 233.570 us; speedup vs baseline: 3.2466x; 1.0186x over previous
//
#include <hip/hip_runtime.h>

#define NN 50000
#define NE 640000
#define DF 128
#define BM 64
#define BK 32
#define NB ((NN + 255) / 256)  // 196 scan blocks

__device__ inline unsigned bf16rne(float f) {
  unsigned u = __float_as_uint(f);
  return (u + 0x7fff + ((u >> 16) & 1)) >> 16;
}
__device__ inline float bflo(unsigned u) { return __uint_as_float(u << 16); }
__device__ inline float bfhi(unsigned u) { return __uint_as_float(u & 0xffff0000u); }

// ---------------- CSR build ----------------

__global__ __launch_bounds__(256) void k_count(const int* __restrict__ ei, int* __restrict__ degi) {
  int e = blockIdx.x * 256 + threadIdx.x;
  if (e < NE) atomicAdd(&degi[ei[NE + e]], 1);
}

__global__ __launch_bounds__(256) void k_blocksum(const int* __restrict__ degi, int* __restrict__ bsum) {
  int i = blockIdx.x * 256 + threadIdx.x;
  int v = (i < NN) ? degi[i] : 0;
#pragma unroll
  for (int d = 32; d > 0; d >>= 1) v += __shfl_down(v, d, 64);
  __shared__ int s[4];
  if ((threadIdx.x & 63) == 0) s[threadIdx.x >> 6] = v;
  __syncthreads();
  if (threadIdx.x == 0) bsum[blockIdx.x] = s[0] + s[1] + s[2] + s[3];
}

__global__ __launch_bounds__(256) void k_scan_small(const int* __restrict__ bsum, int* __restrict__ bpre) {
  __shared__ int s[256];
  int tid = threadIdx.x;
  int v = (tid < NB) ? bsum[tid] : 0;
  s[tid] = v;
  __syncthreads();
  for (int d = 1; d < 256; d <<= 1) {
    int t = (tid >= d) ? s[tid - d] : 0;
    __syncthreads();
    s[tid] += t;
    __syncthreads();
  }
  if (tid < NB) bpre[tid] = s[tid] - v;  // exclusive
}

__global__ __launch_bounds__(256) void k_offsets(const int* __restrict__ degi, const int* __restrict__ bpre,
                                                 int* __restrict__ off, int* __restrict__ fill,
                                                 float* __restrict__ dinv) {
  __shared__ int s[256];
  int tid = threadIdx.x;
  int i = blockIdx.x * 256 + tid;
  int v = (i < NN) ? degi[i] : 0;
  s[tid] = v;
  __syncthreads();
  for (int d = 1; d < 256; d <<= 1) {
    int t = (tid >= d) ? s[tid - d] : 0;
    __syncthreads();
    s[tid] += t;
    __syncthreads();
  }
  if (i < NN) {
    int o = bpre[blockIdx.x] + s[tid] - v;
    off[i] = o;
    fill[i] = o;
    dinv[i] = rsqrtf((float)(v + 1));  // +1 self-loop
  }
  if (i == NN - 1) off[NN] = NE;
}

__global__ __launch_bounds__(256) void k_scatter(const int* __restrict__ ei, int* __restrict__ fill,
                                                 int* __restrict__ ssrc) {
  int e = blockIdx.x * 256 + threadIdx.x;
  if (e >= NE) return;
  int s = ei[e];
  int d = ei[NE + e];
  int pos = atomicAdd(&fill[d], 1);
  ssrc[pos] = s;
}

// ---------------- GEMM: C_bf16[M,128] = A_f32[M,128] @ W[128,128] ----------------

__global__ __launch_bounds__(256) void k_gemm(const float* __restrict__ A,
                                              const float* __restrict__ W,
                                              unsigned* __restrict__ C) {
  __shared__ float As[BK][BM + 4];
  __shared__ float Ws[BK][DF];

  int tid = threadIdx.x;
  int brow = blockIdx.x * BM;

  int rg = tid >> 5;
  int cg = tid & 31;
  int ar = tid >> 2;
  int ac = (tid & 3) * 8;

  float4 acc[8];
#pragma unroll
  for (int r = 0; r < 8; ++r) acc[r] = make_float4(0.f, 0.f, 0.f, 0.f);

  for (int k0 = 0; k0 < DF; k0 += BK) {
    float4 a0 = make_float4(0.f, 0.f, 0.f, 0.f), a1 = a0;
    if (brow + ar < NN) {
      const float4* ap = (const float4*)(A + (size_t)(brow + ar) * DF + k0 + ac);
      a0 = ap[0];
      a1 = ap[1];
    }
    const float4* wg = (const float4*)(W + (size_t)k0 * DF);
    float4 w0 = wg[tid], w1 = wg[tid + 256], w2 = wg[tid + 512], w3 = wg[tid + 768];

    __syncthreads();

    As[ac + 0][ar] = a0.x; As[ac + 1][ar] = a0.y;
    As[ac + 2][ar] = a0.z; As[ac + 3][ar] = a0.w;
    As[ac + 4][ar] = a1.x; As[ac + 5][ar] = a1.y;
    As[ac + 6][ar] = a1.z; As[ac + 7][ar] = a1.w;

    float4* wl = (float4*)&Ws[0][0];
    wl[tid] = w0; wl[tid + 256] = w1; wl[tid + 512] = w2; wl[tid + 768] = w3;

    __syncthreads();

#pragma unroll 4
    for (int kk = 0; kk < BK; ++kk) {
      float4 av0 = *(const float4*)&As[kk][rg * 8];
      float4 av1 = *(const float4*)&As[kk][rg * 8 + 4];
      float4 wv = *(const float4*)&Ws[kk][cg * 4];
      float a_[8] = {av0.x, av0.y, av0.z, av0.w, av1.x, av1.y, av1.z, av1.w};
#pragma unroll
      for (int r = 0; r < 8; ++r) {
        acc[r].x = fmaf(a_[r], wv.x, acc[r].x);
        acc[r].y = fmaf(a_[r], wv.y, acc[r].y);
        acc[r].z = fmaf(a_[r], wv.z, acc[r].z);
        acc[r].w = fmaf(a_[r], wv.w, acc[r].w);
      }
    }
  }

  // epilogue: pack 4 f32 -> 2 uints of bf16 pairs; row = 64 uints
#pragma unroll
  for (int r = 0; r < 8; ++r) {
    int row = brow + rg * 8 + r;
    if (row < NN) {
      uint2 p;
      p.x = bf16rne(acc[r].x) | (bf16rne(acc[r].y) << 16);
      p.y = bf16rne(acc[r].z) | (bf16rne(acc[r].w) << 16);
      *(uint2*)(C + (size_t)row * (DF / 2) + cg * 2) = p;
    }
  }
}

// ---------------- Aggregation: one wave per node, bf16 gather rows ----------------
// out[i] = relu?( sum_e dinv[s_e]*dinv[i]*h[s_e] + dinv[i]^2*h[i] + bias )

__global__ __launch_bounds__(256) void k_agg(const unsigned* __restrict__ h, const float* __restrict__ dinv,
                                             const int* __restrict__ off, const int* __restrict__ ssrc,
                                             const float* __restrict__ bias,
                                             float* __restrict__ out, int do_relu) {
  int gw = (blockIdx.x * 256 + threadIdx.x) >> 6;
  int lane = threadIdx.x & 63;
  if (gw >= NN) return;

  float di = dinv[gw];
  float w0s = di * di;
  unsigned us = h[(size_t)gw * 64 + lane];
  float2 a0 = make_float2(bflo(us) * w0s, bfhi(us) * w0s);
  float2 a1 = make_float2(0.f, 0.f), a2 = a1, a3 = a1;

  int e = off[gw], e1 = off[gw + 1];
  for (; e < e1; e += 8) {
    int last = e1 - 1;
    int i1 = min(e + 1, last), i2 = min(e + 2, last), i3 = min(e + 3, last);
    int i4 = min(e + 4, last), i5 = min(e + 5, last), i6 = min(e + 6, last), i7 = min(e + 7, last);
    int s0 = ssrc[e],  s1 = ssrc[i1], s2 = ssrc[i2], s3 = ssrc[i3];
    int s4 = ssrc[i4], s5 = ssrc[i5], s6 = ssrc[i6], s7 = ssrc[i7];
    float w0 = dinv[s0] * di;
    float w1 = (e + 1 <= last) ? dinv[s1] * di : 0.f;
    float w2 = (e + 2 <= last) ? dinv[s2] * di : 0.f;
    float w3 = (e + 3 <= last) ? dinv[s3] * di : 0.f;
    float w4 = (e + 4 <= last) ? dinv[s4] * di : 0.f;
    float w5 = (e + 5 <= last) ? dinv[s5] * di : 0.f;
    float w6 = (e + 6 <= last) ? dinv[s6] * di : 0.f;
    float w7 = (e + 7 <= last) ? dinv[s7] * di : 0.f;
    unsigned u0 = h[(size_t)s0 * 64 + lane];
    unsigned u1 = h[(size_t)s1 * 64 + lane];
    unsigned u2 = h[(size_t)s2 * 64 + lane];
    unsigned u3 = h[(size_t)s3 * 64 + lane];
    unsigned u4 = h[(size_t)s4 * 64 + lane];
    unsigned u5 = h[(size_t)s5 * 64 + lane];
    unsigned u6 = h[(size_t)s6 * 64 + lane];
    unsigned u7 = h[(size_t)s7 * 64 + lane];
    a0.x = fmaf(bflo(u0), w0, a0.x); a0.y = fmaf(bfhi(u0), w0, a0.y);
    a1.x = fmaf(bflo(u1), w1, a1.x); a1.y = fmaf(bfhi(u1), w1, a1.y);
    a2.x = fmaf(bflo(u2), w2, a2.x); a2.y = fmaf(bfhi(u2), w2, a2.y);
    a3.x = fmaf(bflo(u3), w3, a3.x); a3.y = fmaf(bfhi(u3), w3, a3.y);
    a0.x = fmaf(bflo(u4), w4, a0.x); a0.y = fmaf(bfhi(u4), w4, a0.y);
    a1.x = fmaf(bflo(u5), w5, a1.x); a1.y = fmaf(bfhi(u5), w5, a1.y);
    a2.x = fmaf(bflo(u6), w6, a2.x); a2.y = fmaf(bfhi(u6), w6, a2.y);
    a3.x = fmaf(bflo(u7), w7, a3.x); a3.y = fmaf(bfhi(u7), w7, a3.y);
  }

  a0.x += a1.x + a2.x + a3.x;
  a0.y += a1.y + a2.y + a3.y;

  float2 b = ((const float2*)bias)[lane];
  a0.x += b.x;
  a0.y += b.y;
  if (do_relu) {
    a0.x = fmaxf(a0.x, 0.f);
    a0.y = fmaxf(a0.y, 0.f);
  }
  ((float2*)(out + (size_t)gw * DF))[lane] = a0;
}

// ---------------- launcher ----------------

extern "C" void kernel_launch(void* const* d_in, const int* in_sizes, int n_in,
                              void* d_out, int out_size, void* d_ws, size_t ws_size,
                              hipStream_t stream) {
  const float* x  = (const float*)d_in[0];
  const int*   ei = (const int*)d_in[1];
  const float* W1 = (const float*)d_in[2];
  const float* b1 = (const float*)d_in[3];
  const float* W2 = (const float*)d_in[4];
  const float* b2 = (const float*)d_in[5];
  float* out = (float*)d_out;

  char* ws = (char*)d_ws;
  unsigned* hT = (unsigned*)ws; ws += (size_t)NN * (DF / 2) * 4;  // 12.8 MB bf16 table (reused both layers)
  int*   ssrc = (int*)ws;   ws += (size_t)NE * 4;
  int*   degi = (int*)ws;   ws += (size_t)NN * 4;
  float* dinv = (float*)ws; ws += (size_t)NN * 4;
  int*   fill = (int*)ws;   ws += (size_t)NN * 4;
  int*   off  = (int*)ws;   ws += (size_t)(NN + 1) * 4;
  int*   bsum = (int*)ws;   ws += (size_t)NB * 4;
  int*   bpre = (int*)ws;   ws += (size_t)NB * 4;
  float* act = out;  // layer-1 activation (f32) in d_out; fully rewritten by final agg

  hipMemsetAsync(degi, 0, (size_t)NN * 4, stream);
  k_count<<<(NE + 255) / 256, 256, 0, stream>>>(ei, degi);
  k_blocksum<<<NB, 256, 0, stream>>>(degi, bsum);
  k_scan_small<<<1, 256, 0, stream>>>(bsum, bpre);
  k_offsets<<<NB, 256, 0, stream>>>(degi, bpre, off, fill, dinv);
  k_scatter<<<(NE + 255) / 256, 256, 0, stream>>>(ei, fill, ssrc);

  k_gemm<<<(NN + BM - 1) / BM, 256, 0, stream>>>(x, W1, hT);
  k_agg<<<(NN * 64 + 255) / 256, 256, 0, stream>>>(hT, dinv, off, ssrc, b1, act, 1);
  k_gemm<<<(NN + BM - 1) / BM, 256, 0, stream>>>(act, W2, hT);
  k_agg<<<(NN * 64 + 255) / 256, 256, 0, stream>>>(hT, dinv, off, ssrc, b2, out, 0);
}

// Round 5
// 203.381 us; speedup vs baseline: 3.7285x; 1.1484x over previous
//
#include <hip/hip_runtime.h>

#define NN 50000
#define NE 640000
#define DF 128
#define BM 64
#define BK 32
#define NB ((NN + 255) / 256)  // 196 scan blocks

__device__ inline unsigned bf16rne(float f) {
  unsigned u = __float_as_uint(f);
  return (u + 0x7fff + ((u >> 16) & 1)) >> 16;
}
__device__ inline float bflo(unsigned u) { return __uint_as_float(u << 16); }
__device__ inline float bfhi(unsigned u) { return __uint_as_float(u & 0xffff0000u); }

// ---------------- CSR build ----------------

__global__ __launch_bounds__(256) void k_count(const int* __restrict__ ei, int* __restrict__ degi) {
  int e = blockIdx.x * 256 + threadIdx.x;
  if (e < NE) atomicAdd(&degi[ei[NE + e]], 1);
}

__global__ __launch_bounds__(256) void k_blocksum(const int* __restrict__ degi, int* __restrict__ bsum) {
  int i = blockIdx.x * 256 + threadIdx.x;
  int v = (i < NN) ? degi[i] : 0;
#pragma unroll
  for (int d = 32; d > 0; d >>= 1) v += __shfl_down(v, d, 64);
  __shared__ int s[4];
  if ((threadIdx.x & 63) == 0) s[threadIdx.x >> 6] = v;
  __syncthreads();
  if (threadIdx.x == 0) bsum[blockIdx.x] = s[0] + s[1] + s[2] + s[3];
}

__global__ __launch_bounds__(256) void k_scan_small(const int* __restrict__ bsum, int* __restrict__ bpre) {
  __shared__ int s[256];
  int tid = threadIdx.x;
  int v = (tid < NB) ? bsum[tid] : 0;
  s[tid] = v;
  __syncthreads();
  for (int d = 1; d < 256; d <<= 1) {
    int t = (tid >= d) ? s[tid - d] : 0;
    __syncthreads();
    s[tid] += t;
    __syncthreads();
  }
  if (tid < NB) bpre[tid] = s[tid] - v;  // exclusive
}

__global__ __launch_bounds__(256) void k_offsets(const int* __restrict__ degi, const int* __restrict__ bpre,
                                                 int* __restrict__ off, int* __restrict__ fill,
                                                 float* __restrict__ dinv) {
  __shared__ int s[256];
  int tid = threadIdx.x;
  int i = blockIdx.x * 256 + tid;
  int v = (i < NN) ? degi[i] : 0;
  s[tid] = v;
  __syncthreads();
  for (int d = 1; d < 256; d <<= 1) {
    int t = (tid >= d) ? s[tid - d] : 0;
    __syncthreads();
    s[tid] += t;
    __syncthreads();
  }
  if (i < NN) {
    int o = bpre[blockIdx.x] + s[tid] - v;
    off[i] = o;
    fill[i] = o;
    dinv[i] = rsqrtf((float)(v + 1));  // +1 self-loop
  }
  if (i == NN - 1) off[NN] = NE;
}

__global__ __launch_bounds__(256) void k_scatter(const int* __restrict__ ei, int* __restrict__ fill,
                                                 int* __restrict__ ssrc) {
  int e = blockIdx.x * 256 + threadIdx.x;
  if (e >= NE) return;
  int s = ei[e];
  int d = ei[NE + e];
  int pos = atomicAdd(&fill[d], 1);
  ssrc[pos] = s;
}

// ---------------- GEMM: C_bf16[M,128] = A_f32[M,128] @ W[128,128] ----------------

__global__ __launch_bounds__(256) void k_gemm(const float* __restrict__ A,
                                              const float* __restrict__ W,
                                              unsigned* __restrict__ C) {
  __shared__ float As[BK][BM + 4];
  __shared__ float Ws[BK][DF];

  int tid = threadIdx.x;
  int brow = blockIdx.x * BM;

  int rg = tid >> 5;
  int cg = tid & 31;
  int ar = tid >> 2;
  int ac = (tid & 3) * 8;

  float4 acc[8];
#pragma unroll
  for (int r = 0; r < 8; ++r) acc[r] = make_float4(0.f, 0.f, 0.f, 0.f);

  for (int k0 = 0; k0 < DF; k0 += BK) {
    float4 a0 = make_float4(0.f, 0.f, 0.f, 0.f), a1 = a0;
    if (brow + ar < NN) {
      const float4* ap = (const float4*)(A + (size_t)(brow + ar) * DF + k0 + ac);
      a0 = ap[0];
      a1 = ap[1];
    }
    const float4* wg = (const float4*)(W + (size_t)k0 * DF);
    float4 w0 = wg[tid], w1 = wg[tid + 256], w2 = wg[tid + 512], w3 = wg[tid + 768];

    __syncthreads();

    As[ac + 0][ar] = a0.x; As[ac + 1][ar] = a0.y;
    As[ac + 2][ar] = a0.z; As[ac + 3][ar] = a0.w;
    As[ac + 4][ar] = a1.x; As[ac + 5][ar] = a1.y;
    As[ac + 6][ar] = a1.z; As[ac + 7][ar] = a1.w;

    float4* wl = (float4*)&Ws[0][0];
    wl[tid] = w0; wl[tid + 256] = w1; wl[tid + 512] = w2; wl[tid + 768] = w3;

    __syncthreads();

#pragma unroll 4
    for (int kk = 0; kk < BK; ++kk) {
      float4 av0 = *(const float4*)&As[kk][rg * 8];
      float4 av1 = *(const float4*)&As[kk][rg * 8 + 4];
      float4 wv = *(const float4*)&Ws[kk][cg * 4];
      float a_[8] = {av0.x, av0.y, av0.z, av0.w, av1.x, av1.y, av1.z, av1.w};
#pragma unroll
      for (int r = 0; r < 8; ++r) {
        acc[r].x = fmaf(a_[r], wv.x, acc[r].x);
        acc[r].y = fmaf(a_[r], wv.y, acc[r].y);
        acc[r].z = fmaf(a_[r], wv.z, acc[r].z);
        acc[r].w = fmaf(a_[r], wv.w, acc[r].w);
      }
    }
  }

#pragma unroll
  for (int r = 0; r < 8; ++r) {
    int row = brow + rg * 8 + r;
    if (row < NN) {
      uint2 p;
      p.x = bf16rne(acc[r].x) | (bf16rne(acc[r].y) << 16);
      p.y = bf16rne(acc[r].z) | (bf16rne(acc[r].w) << 16);
      *(uint2*)(C + (size_t)row * (DF / 2) + cg * 2) = p;
    }
  }
}

// ---------------- Aggregation: one wave per node; quarter-wave row gathers ----------------
// Each 16-lane quarter loads one full 256B bf16 row as uint4 (16B/lane).
// One dwordx4 instruction = 4 edge rows. acc[8] f32 per lane (cols 8c..8c+7),
// final shfl_xor(16,32) reduce; lanes q<2 write float4 halves.

__global__ __launch_bounds__(256) void k_agg(const unsigned* __restrict__ h, const float* __restrict__ dinv,
                                             const int* __restrict__ off, const int* __restrict__ ssrc,
                                             const float* __restrict__ bias,
                                             float* __restrict__ out, int do_relu) {
  int gw = (blockIdx.x * 256 + threadIdx.x) >> 6;
  int lane = threadIdx.x & 63;
  if (gw >= NN) return;

  int c = lane & 15;   // 16B chunk within row
  int q = lane >> 4;   // quarter id = which edge in group of 4

  float di = dinv[gw];

  float acc[8];
  // self-loop: all quarters load the same self chunk (L1-merged); only q==0 weighted
  {
    float w = (q == 0) ? di * di : 0.f;
    uint4 u = *((const uint4*)(h + (size_t)gw * 64) + c);
    acc[0] = bflo(u.x) * w; acc[1] = bfhi(u.x) * w;
    acc[2] = bflo(u.y) * w; acc[3] = bfhi(u.y) * w;
    acc[4] = bflo(u.z) * w; acc[5] = bfhi(u.z) * w;
    acc[6] = bflo(u.w) * w; acc[7] = bfhi(u.w) * w;
  }

  int e = off[gw], e1 = off[gw + 1];
  for (int e0 = e; e0 < e1; e0 += 8) {
    int li = e0 + (lane & 7);
    int idx = min(li, e1 - 1);
    int sv = ssrc[idx];                       // coalesced 32B
    float dv = (li < e1) ? dinv[sv] * di : 0.f;

#pragma unroll
    for (int g = 0; g < 2; ++g) {
      int edge = g * 4 + q;
      int s = __shfl(sv, edge);
      float w = __shfl(dv, edge);
      uint4 u = *((const uint4*)(h + (size_t)s * 64) + c);
      acc[0] = fmaf(bflo(u.x), w, acc[0]); acc[1] = fmaf(bfhi(u.x), w, acc[1]);
      acc[2] = fmaf(bflo(u.y), w, acc[2]); acc[3] = fmaf(bfhi(u.y), w, acc[3]);
      acc[4] = fmaf(bflo(u.z), w, acc[4]); acc[5] = fmaf(bfhi(u.z), w, acc[5]);
      acc[6] = fmaf(bflo(u.w), w, acc[6]); acc[7] = fmaf(bfhi(u.w), w, acc[7]);
    }
  }

  // reduce across quarters: lanes {c, c+16, c+32, c+48} hold same cols
#pragma unroll
  for (int j = 0; j < 8; ++j) {
    acc[j] += __shfl_xor(acc[j], 16);
    acc[j] += __shfl_xor(acc[j], 32);
  }

  if (q < 2) {
    int col0 = c * 8 + q * 4;
    float4 b4 = *(const float4*)(bias + col0);
    float4 o;
    o.x = acc[q * 4 + 0] + b4.x;
    o.y = acc[q * 4 + 1] + b4.y;
    o.z = acc[q * 4 + 2] + b4.z;
    o.w = acc[q * 4 + 3] + b4.w;
    if (do_relu) {
      o.x = fmaxf(o.x, 0.f); o.y = fmaxf(o.y, 0.f);
      o.z = fmaxf(o.z, 0.f); o.w = fmaxf(o.w, 0.f);
    }
    *(float4*)(out + (size_t)gw * DF + col0) = o;
  }
}

// ---------------- launcher ----------------

extern "C" void kernel_launch(void* const* d_in, const int* in_sizes, int n_in,
                              void* d_out, int out_size, void* d_ws, size_t ws_size,
                              hipStream_t stream) {
  const float* x  = (const float*)d_in[0];
  const int*   ei = (const int*)d_in[1];
  const float* W1 = (const float*)d_in[2];
  const float* b1 = (const float*)d_in[3];
  const float* W2 = (const float*)d_in[4];
  const float* b2 = (const float*)d_in[5];
  float* out = (float*)d_out;

  char* ws = (char*)d_ws;
  unsigned* hT = (unsigned*)ws; ws += (size_t)NN * (DF / 2) * 4;  // 12.8 MB bf16 table
  int*   ssrc = (int*)ws;   ws += (size_t)NE * 4;
  int*   degi = (int*)ws;   ws += (size_t)NN * 4;
  float* dinv = (float*)ws; ws += (size_t)NN * 4;
  int*   fill = (int*)ws;   ws += (size_t)NN * 4;
  int*   off  = (int*)ws;   ws += (size_t)(NN + 1) * 4;
  int*   bsum = (int*)ws;   ws += (size_t)NB * 4;
  int*   bpre = (int*)ws;   ws += (size_t)NB * 4;
  float* act = out;  // layer-1 activation (f32) in d_out; fully rewritten by final agg

  hipMemsetAsync(degi, 0, (size_t)NN * 4, stream);
  k_count<<<(NE + 255) / 256, 256, 0, stream>>>(ei, degi);
  k_blocksum<<<NB, 256, 0, stream>>>(degi, bsum);
  k_scan_small<<<1, 256, 0, stream>>>(bsum, bpre);
  k_offsets<<<NB, 256, 0, stream>>>(degi, bpre, off, fill, dinv);
  k_scatter<<<(NE + 255) / 256, 256, 0, stream>>>(ei, fill, ssrc);

  k_gemm<<<(NN + BM - 1) / BM, 256, 0, stream>>>(x, W1, hT);
  k_agg<<<(NN * 64 + 255) / 256, 256, 0, stream>>>(hT, dinv, off, ssrc, b1, act, 1);
  k_gemm<<<(NN + BM - 1) / BM, 256, 0, stream>>>(act, W2, hT);
  k_agg<<<(NN * 64 + 255) / 256, 256, 0, stream>>>(hT, dinv, off, ssrc, b2, out, 0);
}

// Round 6
// 180.240 us; speedup vs baseline: 4.2072x; 1.1284x over previous
//
#include <hip/hip_runtime.h>

#define NN 50000
#define NE 640000
#define DF 128
#define BM 64
#define BK 32
#define NB ((NN + 255) / 256)  // 196 scan blocks

__device__ inline unsigned bf16rne(float f) {
  unsigned u = __float_as_uint(f);
  return (u + 0x7fff + ((u >> 16) & 1)) >> 16;
}
__device__ inline float bflo(unsigned u) { return __uint_as_float(u << 16); }
__device__ inline float bfhi(unsigned u) { return __uint_as_float(u & 0xffff0000u); }

// ---------------- CSR build ----------------

__global__ __launch_bounds__(256) void k_zero(int* __restrict__ degi) {
  int i = blockIdx.x * 256 + threadIdx.x;
  if (i < NN) degi[i] = 0;
}

// count in-degree AND record each edge's rank within its dst bucket
__global__ __launch_bounds__(256) void k_count(const int* __restrict__ ei, int* __restrict__ degi,
                                               int* __restrict__ rank) {
  int e = blockIdx.x * 256 + threadIdx.x;
  if (e < NE) rank[e] = atomicAdd(&degi[ei[NE + e]], 1);
}

__global__ __launch_bounds__(256) void k_blocksum(const int* __restrict__ degi, int* __restrict__ bsum) {
  int i = blockIdx.x * 256 + threadIdx.x;
  int v = (i < NN) ? degi[i] : 0;
#pragma unroll
  for (int d = 32; d > 0; d >>= 1) v += __shfl_down(v, d, 64);
  __shared__ int s[4];
  if ((threadIdx.x & 63) == 0) s[threadIdx.x >> 6] = v;
  __syncthreads();
  if (threadIdx.x == 0) bsum[blockIdx.x] = s[0] + s[1] + s[2] + s[3];
}

__global__ __launch_bounds__(256) void k_scan_small(const int* __restrict__ bsum, int* __restrict__ bpre) {
  __shared__ int s[256];
  int tid = threadIdx.x;
  int v = (tid < NB) ? bsum[tid] : 0;
  s[tid] = v;
  __syncthreads();
  for (int d = 1; d < 256; d <<= 1) {
    int t = (tid >= d) ? s[tid - d] : 0;
    __syncthreads();
    s[tid] += t;
    __syncthreads();
  }
  if (tid < NB) bpre[tid] = s[tid] - v;  // exclusive
}

__global__ __launch_bounds__(256) void k_offsets(const int* __restrict__ degi, const int* __restrict__ bpre,
                                                 int* __restrict__ off, float* __restrict__ dinv) {
  __shared__ int s[256];
  int tid = threadIdx.x;
  int i = blockIdx.x * 256 + tid;
  int v = (i < NN) ? degi[i] : 0;
  s[tid] = v;
  __syncthreads();
  for (int d = 1; d < 256; d <<= 1) {
    int t = (tid >= d) ? s[tid - d] : 0;
    __syncthreads();
    s[tid] += t;
    __syncthreads();
  }
  if (i < NN) {
    off[i] = bpre[blockIdx.x] + s[tid] - v;
    dinv[i] = rsqrtf((float)(v + 1));  // +1 self-loop
  }
  if (i == NN - 1) off[NN] = NE;
}

// atomic-free scatter: pos = off[dst] + rank[e]
__global__ __launch_bounds__(256) void k_scatter(const int* __restrict__ ei, const int* __restrict__ off,
                                                 const int* __restrict__ rank, int* __restrict__ ssrc) {
  int e = blockIdx.x * 256 + threadIdx.x;
  if (e >= NE) return;
  int s = ei[e];
  int d = ei[NE + e];
  ssrc[off[d] + rank[e]] = s;
}

// ---------------- GEMM: C_bf16[M,128] = A_f32[M,128] @ W[128,128] ----------------

__global__ __launch_bounds__(256) void k_gemm(const float* __restrict__ A,
                                              const float* __restrict__ W,
                                              unsigned* __restrict__ C) {
  __shared__ float As[BK][BM + 4];
  __shared__ float Ws[BK][DF];

  int tid = threadIdx.x;
  int brow = blockIdx.x * BM;

  int rg = tid >> 5;
  int cg = tid & 31;
  int ar = tid >> 2;
  int ac = (tid & 3) * 8;

  float4 acc[8];
#pragma unroll
  for (int r = 0; r < 8; ++r) acc[r] = make_float4(0.f, 0.f, 0.f, 0.f);

  for (int k0 = 0; k0 < DF; k0 += BK) {
    float4 a0 = make_float4(0.f, 0.f, 0.f, 0.f), a1 = a0;
    if (brow + ar < NN) {
      const float4* ap = (const float4*)(A + (size_t)(brow + ar) * DF + k0 + ac);
      a0 = ap[0];
      a1 = ap[1];
    }
    const float4* wg = (const float4*)(W + (size_t)k0 * DF);
    float4 w0 = wg[tid], w1 = wg[tid + 256], w2 = wg[tid + 512], w3 = wg[tid + 768];

    __syncthreads();

    As[ac + 0][ar] = a0.x; As[ac + 1][ar] = a0.y;
    As[ac + 2][ar] = a0.z; As[ac + 3][ar] = a0.w;
    As[ac + 4][ar] = a1.x; As[ac + 5][ar] = a1.y;
    As[ac + 6][ar] = a1.z; As[ac + 7][ar] = a1.w;

    float4* wl = (float4*)&Ws[0][0];
    wl[tid] = w0; wl[tid + 256] = w1; wl[tid + 512] = w2; wl[tid + 768] = w3;

    __syncthreads();

#pragma unroll 4
    for (int kk = 0; kk < BK; ++kk) {
      float4 av0 = *(const float4*)&As[kk][rg * 8];
      float4 av1 = *(const float4*)&As[kk][rg * 8 + 4];
      float4 wv = *(const float4*)&Ws[kk][cg * 4];
      float a_[8] = {av0.x, av0.y, av0.z, av0.w, av1.x, av1.y, av1.z, av1.w};
#pragma unroll
      for (int r = 0; r < 8; ++r) {
        acc[r].x = fmaf(a_[r], wv.x, acc[r].x);
        acc[r].y = fmaf(a_[r], wv.y, acc[r].y);
        acc[r].z = fmaf(a_[r], wv.z, acc[r].z);
        acc[r].w = fmaf(a_[r], wv.w, acc[r].w);
      }
    }
  }

#pragma unroll
  for (int r = 0; r < 8; ++r) {
    int row = brow + rg * 8 + r;
    if (row < NN) {
      uint2 p;
      p.x = bf16rne(acc[r].x) | (bf16rne(acc[r].y) << 16);
      p.y = bf16rne(acc[r].z) | (bf16rne(acc[r].w) << 16);
      *(uint2*)(C + (size_t)row * (DF / 2) + cg * 2) = p;
    }
  }
}

// ---------------- Aggregation: one wave per node; quarter-wave row gathers ----------------

__global__ __launch_bounds__(256) void k_agg(const unsigned* __restrict__ h, const float* __restrict__ dinv,
                                             const int* __restrict__ off, const int* __restrict__ ssrc,
                                             const float* __restrict__ bias,
                                             float* __restrict__ out, int do_relu) {
  int gw = (blockIdx.x * 256 + threadIdx.x) >> 6;
  int lane = threadIdx.x & 63;
  if (gw >= NN) return;

  int c = lane & 15;   // 16B chunk within row
  int q = lane >> 4;   // quarter id = which edge in group of 4

  float di = dinv[gw];

  float acc[8];
  {
    float w = (q == 0) ? di * di : 0.f;
    uint4 u = *((const uint4*)(h + (size_t)gw * 64) + c);
    acc[0] = bflo(u.x) * w; acc[1] = bfhi(u.x) * w;
    acc[2] = bflo(u.y) * w; acc[3] = bfhi(u.y) * w;
    acc[4] = bflo(u.z) * w; acc[5] = bfhi(u.z) * w;
    acc[6] = bflo(u.w) * w; acc[7] = bfhi(u.w) * w;
  }

  int e = off[gw], e1 = off[gw + 1];
  for (int e0 = e; e0 < e1; e0 += 8) {
    int li = e0 + (lane & 7);
    int idx = min(li, e1 - 1);
    int sv = ssrc[idx];
    float dv = (li < e1) ? dinv[sv] * di : 0.f;

#pragma unroll
    for (int g = 0; g < 2; ++g) {
      int edge = g * 4 + q;
      int s = __shfl(sv, edge);
      float w = __shfl(dv, edge);
      uint4 u = *((const uint4*)(h + (size_t)s * 64) + c);
      acc[0] = fmaf(bflo(u.x), w, acc[0]); acc[1] = fmaf(bfhi(u.x), w, acc[1]);
      acc[2] = fmaf(bflo(u.y), w, acc[2]); acc[3] = fmaf(bfhi(u.y), w, acc[3]);
      acc[4] = fmaf(bflo(u.z), w, acc[4]); acc[5] = fmaf(bfhi(u.z), w, acc[5]);
      acc[6] = fmaf(bflo(u.w), w, acc[6]); acc[7] = fmaf(bfhi(u.w), w, acc[7]);
    }
  }

#pragma unroll
  for (int j = 0; j < 8; ++j) {
    acc[j] += __shfl_xor(acc[j], 16);
    acc[j] += __shfl_xor(acc[j], 32);
  }

  if (q < 2) {
    int col0 = c * 8 + q * 4;
    float4 b4 = *(const float4*)(bias + col0);
    float4 o;
    o.x = acc[q * 4 + 0] + b4.x;
    o.y = acc[q * 4 + 1] + b4.y;
    o.z = acc[q * 4 + 2] + b4.z;
    o.w = acc[q * 4 + 3] + b4.w;
    if (do_relu) {
      o.x = fmaxf(o.x, 0.f); o.y = fmaxf(o.y, 0.f);
      o.z = fmaxf(o.z, 0.f); o.w = fmaxf(o.w, 0.f);
    }
    *(float4*)(out + (size_t)gw * DF + col0) = o;
  }
}

// ---------------- launcher ----------------

extern "C" void kernel_launch(void* const* d_in, const int* in_sizes, int n_in,
                              void* d_out, int out_size, void* d_ws, size_t ws_size,
                              hipStream_t stream) {
  const float* x  = (const float*)d_in[0];
  const int*   ei = (const int*)d_in[1];
  const float* W1 = (const float*)d_in[2];
  const float* b1 = (const float*)d_in[3];
  const float* W2 = (const float*)d_in[4];
  const float* b2 = (const float*)d_in[5];
  float* out = (float*)d_out;

  char* ws = (char*)d_ws;
  unsigned* hT = (unsigned*)ws; ws += (size_t)NN * (DF / 2) * 4;  // 12.8 MB bf16 table
  int*   ssrc = (int*)ws;   ws += (size_t)NE * 4;
  int*   rank = (int*)ws;   ws += (size_t)NE * 4;
  int*   degi = (int*)ws;   ws += (size_t)NN * 4;
  float* dinv = (float*)ws; ws += (size_t)NN * 4;
  int*   off  = (int*)ws;   ws += (size_t)(NN + 1) * 4;
  int*   bsum = (int*)ws;   ws += (size_t)NB * 4;
  int*   bpre = (int*)ws;   ws += (size_t)NB * 4;
  float* act = out;  // layer-1 activation (f32) in d_out; fully rewritten by final agg

  k_zero<<<NB, 256, 0, stream>>>(degi);
  k_count<<<(NE + 255) / 256, 256, 0, stream>>>(ei, degi, rank);
  k_blocksum<<<NB, 256, 0, stream>>>(degi, bsum);
  k_scan_small<<<1, 256, 0, stream>>>(bsum, bpre);
  k_offsets<<<NB, 256, 0, stream>>>(degi, bpre, off, dinv);
  k_scatter<<<(NE + 255) / 256, 256, 0, stream>>>(ei, off, rank, ssrc);

  k_gemm<<<(NN + BM - 1) / BM, 256, 0, stream>>>(x, W1, hT);
  k_agg<<<(NN * 64 + 255) / 256, 256, 0, stream>>>(hT, dinv, off, ssrc, b1, act, 1);
  k_gemm<<<(NN + BM - 1) / BM, 256, 0, stream>>>(act, W2, hT);
  k_agg<<<(NN * 64 + 255) / 256, 256, 0, stream>>>(hT, dinv, off, ssrc, b2, out, 0);
}